// Round 12
// baseline (72.889 us; speedup 1.0000x reference)
//
#include <hip/hip_runtime.h>
#include <math.h>

#define N_CONS  100000
#define N_VARS  200000
#define N_EDGES 8000000
#define N_CAND  20000
#define C_FEAT  5
#define V_FEAT  19
#define BM_WORDS_PAD  6400            // 6250 words padded for vector copies
#define ACC_SLOTS     20000           // max distinct candidates
#define EDGE_BLOCKS   256             // 1 per CU
#define CID_BLOCKS    ((ACC_SLOTS + 255) / 256) // 79

typedef int   i4 __attribute__((ext_vector_type(4)));
typedef float f4 __attribute__((ext_vector_type(4)));

// Pack variable[:,5], constraint[:,2] into dense arrays; build candidate bitmap.
__global__ void pack_kernel(const float* __restrict__ variable,
                            const float* __restrict__ constraint,
                            const int* __restrict__ cand,
                            float* __restrict__ var5,
                            float* __restrict__ cons2,
                            unsigned int* __restrict__ bitmap) {
    int i = blockIdx.x * blockDim.x + threadIdx.x;
    if (i < N_VARS) var5[i]  = variable[i * V_FEAT + 5];
    if (i < N_CONS) cons2[i] = constraint[i * C_FEAT + 2];
    if (i < N_CAND) {
        int v = cand[i];
        atomicOr(&bitmap[v >> 5], 1u << (v & 31));
    }
}

// Edge phase. NEW vs r11:
//  (1) scan merged into the prologue: each block stages the 25KB bitmap,
//      popc-prefix-scans it locally into lds_bp (removes scan_kernel launch
//      + the bp global round-trip). Block 0 publishes bp for out_kernel.
//  (2) ALL read-once streams are NONTEMPORAL (no-allocate): the 96MB edge
//      stream no longer evicts var5/cons2 (1.2MB, L2-fitting) from L2 —
//      theory: the invariant 43us was gather L2-miss traffic to L3 caused
//      by stream-driven eviction, common to every r5-r11 variant.
__global__ void __launch_bounds__(1024, 4)
edge_kernel(const int* __restrict__ c_idx,
            const int* __restrict__ v_idx,
            const float* __restrict__ edge_attr,
            const float* __restrict__ var5,
            const float* __restrict__ cons2,
            const unsigned int* __restrict__ bitmap,
            uint2* __restrict__ bpg,
            float* __restrict__ partials) {
    __shared__ uint2 lds_bp[BM_WORDS_PAD];
    __shared__ float lds_acc[ACC_SLOTS];
    __shared__ unsigned int wsum[16];

    // ---- Prologue 1: stage bitmap into (reused) lds_acc space, coalesced.
    unsigned int* stage = (unsigned int*)lds_acc;
    {
        const uint4* src = (const uint4*)bitmap;
        uint4* dst = (uint4*)stage;
        for (int j = threadIdx.x; j < BM_WORDS_PAD / 4; j += blockDim.x)
            dst[j] = src[j];
    }
    __syncthreads();

    // ---- Prologue 2: local popc-prefix scan -> lds_bp = {word, prefix}.
    {
        const int CH = 7;                       // 7*1024 >= 6400
        int t = threadIdx.x, lane = t & 63, wid = t >> 6;
        int base = t * CH;
        unsigned int w_loc[CH], pf_loc[CH], sum = 0;
#pragma unroll
        for (int j = 0; j < CH; ++j) {
            int w = base + j;
            unsigned int word = (w < BM_WORDS_PAD) ? stage[w] : 0u;
            w_loc[j]  = word;
            pf_loc[j] = sum;
            sum += __popc(word);
        }
        unsigned int inc = sum;
#pragma unroll
        for (int off = 1; off < 64; off <<= 1) {
            unsigned int n = __shfl_up(inc, off, 64);
            if (lane >= off) inc += n;
        }
        if (lane == 63) wsum[wid] = inc;
        __syncthreads();
        if (wid == 0 && lane < 16) {
            unsigned int v = wsum[lane];
#pragma unroll
            for (int off = 1; off < 16; off <<= 1) {
                unsigned int n = __shfl_up(v, off, 16);
                if (lane >= off) v += n;
            }
            wsum[lane] = v;
        }
        __syncthreads();
        unsigned int ebase = inc - sum + (wid ? wsum[wid - 1] : 0u);
#pragma unroll
        for (int j = 0; j < CH; ++j) {
            int w = base + j;
            if (w < BM_WORDS_PAD) lds_bp[w] = make_uint2(w_loc[j], ebase + pf_loc[j]);
        }
    }
    __syncthreads();
    // ---- Prologue 3: zero the accumulator (stage no longer needed).
    for (int j = threadIdx.x; j < ACC_SLOTS; j += blockDim.x)
        lds_acc[j] = 0.0f;
    __syncthreads();

    // ---- Main loop: 8 edges/thread-iter; nontemporal streams.
    const int nch = N_EDGES / 8;
    const int stride = gridDim.x * blockDim.x;
    const i4* v4 = (const i4*)v_idx;
    const i4* c4 = (const i4*)c_idx;
    const f4* e4 = (const f4*)edge_attr;

    for (int g = blockIdx.x * blockDim.x + threadIdx.x; g < nch; g += stride) {
        i4 va = __builtin_nontemporal_load(v4 + 2 * g);
        i4 vb = __builtin_nontemporal_load(v4 + 2 * g + 1);
        i4 ca = __builtin_nontemporal_load(c4 + 2 * g);
        i4 cb = __builtin_nontemporal_load(c4 + 2 * g + 1);
        f4 ea = __builtin_nontemporal_load(e4 + 2 * g);
        f4 eb = __builtin_nontemporal_load(e4 + 2 * g + 1);

#define PROC(vv, cc, ee)                                                     \
        {                                                                    \
            uint2 e2 = lds_bp[(vv) >> 5];                                    \
            if ((e2.x >> ((vv) & 31)) & 1u) {                                \
                int cid = (int)e2.y +                                        \
                          __popc(e2.x & ((1u << ((vv) & 31)) - 1u));         \
                atomicAdd(&lds_acc[cid],                                     \
                          var5[vv] * (ee) + cons2[cc]);                      \
            }                                                                \
        }
        PROC(va[0], ca[0], ea[0])  PROC(va[1], ca[1], ea[1])
        PROC(va[2], ca[2], ea[2])  PROC(va[3], ca[3], ea[3])
        PROC(vb[0], cb[0], eb[0])  PROC(vb[1], cb[1], eb[1])
        PROC(vb[2], cb[2], eb[2])  PROC(vb[3], cb[3], eb[3])
#undef PROC
    }
    __syncthreads();

    // ---- Epilogue: coalesced nontemporal flush of partials.
    {
        f4* dst = (f4*)(partials + (size_t)blockIdx.x * ACC_SLOTS);
        const f4* src = (const f4*)lds_acc;
        for (int j = threadIdx.x; j < ACC_SLOTS / 4; j += blockDim.x)
            __builtin_nontemporal_store(src[j], dst + j);
    }
    // Block 0 publishes the fused bp table for out_kernel.
    if (blockIdx.x == 0) {
        for (int j = threadIdx.x; j < BM_WORDS_PAD; j += blockDim.x)
            bpg[j] = lds_bp[j];
    }
}

// agg2[cid] = sum over the 256 block partials (coalesced columns).
__global__ void reduce_kernel(const float* __restrict__ partials,
                              float* __restrict__ agg2) {
    int cid = blockIdx.x * 256 + threadIdx.x;
    if (cid >= ACC_SLOTS) return;
    float s = 0.0f;
#pragma unroll 8
    for (int k = 0; k < EDGE_BLOCKS; ++k)
        s += __builtin_nontemporal_load(&partials[(size_t)k * ACC_SLOTS + cid]);
    agg2[cid] = s;
}

// out[i] = agg * variable[v,0] + sqrt(abs(variable[v,3])), v = cand[i]
__global__ void out_kernel(const int* __restrict__ cand,
                           const float* __restrict__ agg2,
                           const uint2* __restrict__ bpg,
                           const float* __restrict__ variable,
                           float* __restrict__ out) {
    int i = blockIdx.x * blockDim.x + threadIdx.x;
    if (i >= N_CAND) return;
    int v = cand[i];
    uint2 e2 = bpg[v >> 5];
    int cid = (int)e2.y + __popc(e2.x & ((1u << (v & 31)) - 1u));
    out[i] = agg2[cid] * variable[v * V_FEAT + 0] + sqrtf(fabsf(variable[v * V_FEAT + 3]));
}

extern "C" void kernel_launch(void* const* d_in, const int* in_sizes, int n_in,
                              void* d_out, int out_size, void* d_ws, size_t ws_size,
                              hipStream_t stream) {
    const float* constraint = (const float*)d_in[0];   // [N_CONS, 5]
    const float* variable   = (const float*)d_in[1];   // [N_VARS, 19]
    const int*   cv_edge    = (const int*)d_in[2];     // [2, N_EDGES]
    const float* edge_attr  = (const float*)d_in[3];   // [N_EDGES]
    const int*   cand_mask  = (const int*)d_in[4];     // [N_CAND]
    float* out = (float*)d_out;

    const int* c_idx = cv_edge;            // row 0
    const int* v_idx = cv_edge + N_EDGES;  // row 1

    // ws layout (16B-aligned):
    // var5[200000] f | cons2[100000] f | bitmap[6400] u32 | bp[6400] uint2 |
    // partials[256*20000] f | agg2[20000] f      ~22.3 MB
    float* var5  = (float*)d_ws;
    float* cons2 = var5 + N_VARS;
    unsigned int* bitmap = (unsigned int*)(cons2 + N_CONS);
    uint2* bpg           = (uint2*)(bitmap + BM_WORDS_PAD);
    float* partials      = (float*)(bpg + BM_WORDS_PAD);
    float* agg2          = partials + (size_t)EDGE_BLOCKS * ACC_SLOTS;

    hipMemsetAsync(bitmap, 0, BM_WORDS_PAD * sizeof(unsigned int), stream);

    {
        int threads = 256;
        int blocks = (N_VARS + threads - 1) / threads;
        pack_kernel<<<blocks, threads, 0, stream>>>(variable, constraint, cand_mask,
                                                    var5, cons2, bitmap);
    }
    edge_kernel<<<EDGE_BLOCKS, 1024, 0, stream>>>(c_idx, v_idx, edge_attr,
                                                  var5, cons2, bitmap, bpg,
                                                  partials);
    reduce_kernel<<<CID_BLOCKS, 256, 0, stream>>>(partials, agg2);
    {
        int threads = 256;
        int blocks = (N_CAND + threads - 1) / threads;
        out_kernel<<<blocks, threads, 0, stream>>>(cand_mask, agg2, bpg, variable, out);
    }
}